// Round 2
// baseline (420.692 us; speedup 1.0000x reference)
//
#include <hip/hip_runtime.h>

// FoldLayer (col2im overlap-add), gather formulation — race-free, each input
// element read <=1 time, each output element written exactly once.
//
// Shapes: patches (B=16, GH=64, GW=64, K*K*C = 9*128) fp32, kernel-major.
// out (B, 128, 128, C=128) fp32, after cropping pad=1 from the 130x130 canvas.
//
// Gather rule for padded coord hp = oh+1 in [1,128]:
//   yA = hp>>1, iA = hp&1   -> valid if yA <= 63
//   yB = yA-1,  i  = 2      -> valid if hp even  (then yB >= 0 automatically)
// Same for wp/x/j. 1..4 contributions per output element.

#define GH 64
#define GW 64
#define C  128

__global__ __launch_bounds__(256) void fold_gather_kernel(
    const float4* __restrict__ p, float4* __restrict__ out) {
    int tid = blockIdx.x * 256 + threadIdx.x;
    int c4  = tid & 31;            // float4 channel group, 32 per pixel
    int pix = tid >> 5;            // b*128*128 + oh*128 + ow
    int ow  = pix & 127;
    int oh  = (pix >> 7) & 127;
    int b   = pix >> 14;

    int hp = oh + 1, wp = ow + 1;
    int yA = hp >> 1, iA = hp & 1;
    int xA = wp >> 1, jA = wp & 1;
    bool hA = (yA < GH);           // false only at oh=127 (hp=128)
    bool hB = (iA == 0);           // even hp -> (yA-1, i=2) contribution
    bool wA = (xA < GW);
    bool wB = (jA == 0);

    const int PSTRIDE = (3 * 3 * C) / 4;      // 288 float4 per patch
    int rowA = (b * GH + yA) * GW;            // patch row base for y = yA
    int rowB = rowA - GW;                     // patch row base for y = yA-1

    float4 acc = {0.f, 0.f, 0.f, 0.f};
    auto add = [&](bool valid, int row, int xx, int ii, int jj) {
        if (valid) {
            float4 v = p[(row + xx) * PSTRIDE + (ii * 3 + jj) * 32 + c4];
            acc.x += v.x; acc.y += v.y; acc.z += v.z; acc.w += v.w;
        }
    };
    add(hA && wA, rowA, xA,     iA, jA);
    add(hA && wB, rowA, xA - 1, iA, 2);
    add(hB && wA, rowB, xA,     2,  jA);
    add(hB && wB, rowB, xA - 1, 2,  2);

    out[pix * 32 + c4] = acc;   // fully coalesced float4 store
}

extern "C" void kernel_launch(void* const* d_in, const int* in_sizes, int n_in,
                              void* d_out, int out_size, void* d_ws, size_t ws_size,
                              hipStream_t stream) {
    const float4* p = (const float4*)d_in[0];
    float4* out = (float4*)d_out;
    int total_threads = out_size / 4;          // 16*128*128*128 / 4 = 8,388,608
    dim3 block(256);
    dim3 grid(total_threads / 256);            // 32,768 blocks
    fold_gather_kernel<<<grid, block, 0, stream>>>(p, out);
}

// Round 4
// 418.678 us; speedup vs baseline: 1.0048x; 1.0048x over previous
//
#include <hip/hip_runtime.h>

// FoldLayer (col2im overlap-add), gather formulation — race-free, each input
// element read <=1 time, each output element written exactly once.
//
// v4: same as v3 but with clang ext_vector_type float4 (HIP_vector_type is a
// struct and __builtin_nontemporal_* rejects it).
//
// Shapes: patches (B=16, GH=64, GW=64, K*K*C = 9*128) fp32, kernel-major.
// out (B, 128, 128, C=128) fp32 (pad=1 cropped from the 130x130 canvas).
//
// Gather rule for padded coord hp = oh+1 in [1,128]:
//   (y = hp>>1, i = hp&1)  valid if y <= 63
//   (y = (hp>>1)-1, i = 2) valid if hp even
// Same for wp/x/j. 1..4 contributions per output element.

#define GH 64
#define GW 64

typedef float v4f __attribute__((ext_vector_type(4)));

__global__ __launch_bounds__(256) void fold_gather_kernel(
    const v4f* __restrict__ p, v4f* __restrict__ out) {
    const int PSTRIDE = 288;                    // 3*3*128/4 float4 per patch
    const int BSTRIDE_IN  = GH * GW * PSTRIDE;  // per-batch input float4
    const int BSTRIDE_OUT = 128 * 128 * 32;     // per-batch output float4

    int tid = blockIdx.x * 256 + threadIdx.x;
    int c4  = tid & 31;            // float4 channel group, 32 per pixel
    int pix = tid >> 5;            // b*128*128 + oh*128 + ow, b in [0,8)
    int ow  = pix & 127;
    int oh  = (pix >> 7) & 127;
    int b   = pix >> 14;           // [0,8); partner batch is b+8

    int hp = oh + 1, wp = ow + 1;
    int yA = hp >> 1, iA = hp & 1;
    int xA = wp >> 1, jA = wp & 1;
    bool hA = (yA < GH);           // false only at oh=127
    bool hB = (iA == 0);           // even hp -> (yA-1, i=2) contribution
    bool wA = (xA < GW);
    bool wB = (jA == 0);

    int rowA = (b * GH + yA) * GW; // patch row base for y = yA (batch b)
    int rowB = rowA - GW;          // patch row base for y = yA-1

    v4f acc0 = {0.f, 0.f, 0.f, 0.f};
    v4f acc1 = {0.f, 0.f, 0.f, 0.f};
    auto add = [&](bool valid, int row, int xx, int ii, int jj) {
        if (valid) {
            int idx = (row + xx) * PSTRIDE + (ii * 3 + jj) * 32 + c4;
            v4f v0 = __builtin_nontemporal_load(&p[idx]);
            v4f v1 = __builtin_nontemporal_load(&p[idx + 8 * BSTRIDE_IN]);
            acc0 += v0;
            acc1 += v1;
        }
    };
    add(hA && wA, rowA, xA,     iA, jA);
    add(hA && wB, rowA, xA - 1, iA, 2);
    add(hB && wA, rowB, xA,     2,  jA);
    add(hB && wB, rowB, xA - 1, 2,  2);

    int oidx = pix * 32 + c4;
    __builtin_nontemporal_store(acc0, &out[oidx]);
    __builtin_nontemporal_store(acc1, &out[oidx + 8 * BSTRIDE_OUT]);
}

extern "C" void kernel_launch(void* const* d_in, const int* in_sizes, int n_in,
                              void* d_out, int out_size, void* d_ws, size_t ws_size,
                              hipStream_t stream) {
    const v4f* p = (const v4f*)d_in[0];
    v4f* out = (v4f*)d_out;
    int total_threads = out_size / 8;          // 2 batches per thread -> 4,194,304
    dim3 block(256);
    dim3 grid(total_threads / 256);            // 16,384 blocks
    fold_gather_kernel<<<grid, block, 0, stream>>>(p, out);
}